// Round 1
// baseline (473.547 us; speedup 1.0000x reference)
//
#include <hip/hip_runtime.h>

#define N_PTS 131072
#define LOG2_T 19
#define TABLE_SIZE (1u << LOG2_T)
#define HASH_MASK (TABLE_SIZE - 1u)

// thread layout: 64 combos (4 encodings x 16 levels), each combo covers all
// 131072 points with 512 blocks x 256 threads (point index fastest).
// XCD swizzle: combo c is processed by XCD (c & 7) so one 4MB level-table
// fits that XCD's 4MB L2 while active. Bijective mapping.
__global__ __launch_bounds__(256) void earth4d_kernel(
    const float* __restrict__ xyzt,
    const float* __restrict__ tab_xyz,
    const float* __restrict__ tab_xyt,
    const float* __restrict__ tab_yzt,
    const float* __restrict__ tab_xzt,
    float* __restrict__ out)
{
    unsigned b   = blockIdx.x;          // 0..32767
    unsigned xcd = b & 7u;
    unsigned i   = b >> 3;              // 0..4095
    unsigned combo = ((i >> 9) << 3) | xcd;   // 0..63, combo%8==xcd
    unsigned chunk = i & 511u;                // 0..511
    unsigned e = combo >> 4;                  // encoding 0..3
    unsigned l = combo & 15u;                 // level 0..15
    unsigned n = (chunk << 8) | threadIdx.x;  // point 0..131071

    float4 p = reinterpret_cast<const float4*>(xyzt)[n];

    float c0, c1, c2;
    const float* tab;
    switch (e) {
      case 0:  c0 = p.x; c1 = p.y; c2 = p.z; tab = tab_xyz; break;  // xyz
      case 1:  c0 = p.x; c1 = p.y; c2 = p.w; tab = tab_xyt; break;  // xyt
      case 2:  c0 = p.y; c1 = p.z; c2 = p.w; tab = tab_yzt; break;  // yzt
      default: c0 = p.x; c1 = p.z; c2 = p.w; tab = tab_xzt; break;  // xzt
    }
    const float2* tl = reinterpret_cast<const float2*>(tab) + (size_t)l * TABLE_SIZE;

    unsigned resu = 32u << l;           // 32 * 2^l, exact
    float res = (float)resu;
    float p0 = c0 * res, p1 = c1 * res, p2 = c2 * res;   // exact (res = 2^k)
    float f0 = floorf(p0), f1 = floorf(p1), f2 = floorf(p2);
    float w0 = p0 - f0, w1 = p1 - f1, w2 = p2 - f2;
    int b0 = (int)f0, b1 = (int)f1, b2 = (int)f2;

    unsigned idx[8];
    if (l < 2u) {
        // dense: (res+1)^3 <= 2^19 only for res in {32, 64}
        int s = (int)resu + 1;
        #pragma unroll
        for (int c = 0; c < 8; ++c) {
            int i0 = b0 + ((c >> 2) & 1);
            int i1 = b1 + ((c >> 1) & 1);
            int i2 = b2 + (c & 1);
            idx[c] = (unsigned)(i0 + i1 * s + i2 * s * s);
        }
    } else {
        #pragma unroll
        for (int c = 0; c < 8; ++c) {
            unsigned i0 = (unsigned)(b0 + ((c >> 2) & 1));
            unsigned i1 = (unsigned)(b1 + ((c >> 1) & 1));
            unsigned i2 = (unsigned)(b2 + (c & 1));
            idx[c] = (i0 * 1u ^ i1 * 2654435761u ^ i2 * 805459861u) & HASH_MASK;
        }
    }

    float acc0 = 0.f, acc1 = 0.f;
    #pragma unroll
    for (int c = 0; c < 8; ++c) {
        float2 f = tl[idx[c]];
        float wt = ((c & 4) ? w0 : 1.f - w0)
                 * ((c & 2) ? w1 : 1.f - w1)
                 * ((c & 1) ? w2 : 1.f - w2);
        acc0 = fmaf(f.x, wt, acc0);
        acc1 = fmaf(f.y, wt, acc1);
    }

    // out[n, e*32 + l*2 + f]  (combo*2 == e*32 + l*2)
    float2* o = reinterpret_cast<float2*>(out + (size_t)n * 128u + combo * 2u);
    *o = make_float2(acc0, acc1);
}

extern "C" void kernel_launch(void* const* d_in, const int* in_sizes, int n_in,
                              void* d_out, int out_size, void* d_ws, size_t ws_size,
                              hipStream_t stream) {
    const float* xyzt    = (const float*)d_in[0];
    const float* tab_xyz = (const float*)d_in[1];
    const float* tab_xyt = (const float*)d_in[2];
    const float* tab_yzt = (const float*)d_in[3];
    const float* tab_xzt = (const float*)d_in[4];
    float* out = (float*)d_out;

    // 64 combos * 512 chunks = 32768 blocks of 256 threads
    dim3 grid(64u * 512u), block(256u);
    earth4d_kernel<<<grid, block, 0, stream>>>(xyzt, tab_xyz, tab_xyt, tab_yzt, tab_xzt, out);
}